// Round 18
// baseline (206.736 us; speedup 1.0000x reference)
//
#include <hip/hip_runtime.h>
#include <hip/hip_bf16.h>

typedef float f32x4 __attribute__((ext_vector_type(4)));
typedef float f32x16 __attribute__((ext_vector_type(16)));
typedef short bf16x8 __attribute__((ext_vector_type(8)));
typedef unsigned short ushort8_t __attribute__((ext_vector_type(8)));

#define L_SEQ 4096
#define DMODEL 768
#define NHEAD 12
#define HDIM 64
#define QSCALE (0.125f * 1.44269504f)   // 1/sqrt(64) * log2(e)

__device__ __forceinline__ unsigned short f2bf(float f) {
    __hip_bfloat16 h = __float2bfloat16(f);
    return *reinterpret_cast<unsigned short*>(&h);
}

// HW packed conversion: dst.lo = bf16(a), dst.hi = bf16(b)  (T12 recipe)
__device__ __forceinline__ unsigned pack2bf(float a, float b) {
    unsigned r;
    asm("v_cvt_pk_bf16_f32 %0, %1, %2" : "=v"(r) : "v"(a), "v"(b));
    return r;
}

__device__ __forceinline__ void gload16(const void* g, void* l) {
    __builtin_amdgcn_global_load_lds(
        (const __attribute__((address_space(1))) unsigned int*)g,
        (__attribute__((address_space(3))) unsigned int*)l, 16, 0, 0);
}

// ---------------- fp32 -> bf16 conversion (3 tensors, one dispatch) -------
__global__ __launch_bounds__(256) void cvt3_f32_bf16(
    const float* __restrict__ a, unsigned short* __restrict__ oa, int na,
    const float* __restrict__ bsrc, unsigned short* __restrict__ ob, int nb,
    const float* __restrict__ csrc, unsigned short* __restrict__ oc, int nc)
{
    int i = (blockIdx.x * 256 + threadIdx.x) * 4;
    const float* in; unsigned short* out;
    if (i < na) { in = a; out = oa; }
    else if (i < na + nb) { in = bsrc; out = ob; i -= na; }
    else if (i < na + nb + nc) { in = csrc; out = oc; i -= na + nb; }
    else return;
    float4 v = *reinterpret_cast<const float4*>(in + i);
    ushort4 o;
    o.x = f2bf(v.x); o.y = f2bf(v.y); o.z = f2bf(v.z); o.w = f2bf(v.w);
    *reinterpret_cast<ushort4*>(out + i) = o;
}

#define BM 128
#define BN 128
#define BKK 64

// ------- GEMM1 + fused RMSnorm/RoPE/scale/transpose epilogue --------------
// 1-D grid of 1152, XCD-swizzled: wgid = (lin%8)*144 + lin/8.
__global__ __launch_bounds__(256) void gemm_qkv_fused(
    const unsigned short* __restrict__ A, const unsigned short* __restrict__ Bt,
    const float* __restrict__ cosb, const float* __restrict__ sinb,
    const float* __restrict__ qw, const float* __restrict__ kw,
    unsigned short* __restrict__ Qb, unsigned short* __restrict__ Kb,
    unsigned short* __restrict__ Vt)
{
    __shared__ union SM {
        struct { unsigned short As[BM][BKK]; unsigned short Bs[BN][BKK]; } st;
        unsigned short ep[4][64][72];
    } sm;

    const int K = DMODEL;
    const int lin = blockIdx.x;                       // 0..1151
    const int wgid = (lin & 7) * 144 + (lin >> 3);    // XCD-contiguous
    const int bx = wgid % 18, by = wgid / 18;
    const int tid  = threadIdx.x;
    const int lane = tid & 63;
    const int wid  = tid >> 6;
    const int r = lane & 15, g = lane >> 4;
    const int wr = wid >> 1, wc = wid & 1;
    const int m0 = by * BM;
    const int n0 = bx * BN;

    f32x4 acc[4][4];
    for (int i = 0; i < 4; ++i)
        for (int j = 0; j < 4; ++j)
            acc[i][j] = (f32x4){0.f, 0.f, 0.f, 0.f};

    for (int kt = 0; kt < K; kt += BKK) {
        __syncthreads();
        for (int p = 0; p < 4; ++p) {
            int idx = wid * 64 + p * 256 + lane;
            int row = idx >> 3;
            int ch  = (idx & 7) * 8;
            gload16(&A[(size_t)(m0 + row) * K + kt + ch],
                    (char*)sm.st.As + (size_t)(wid * 64 + p * 256) * 16);
            gload16(&Bt[(size_t)(n0 + row) * K + kt + ch],
                    (char*)sm.st.Bs + (size_t)(wid * 64 + p * 256) * 16);
        }
        __syncthreads();
        for (int k0 = 0; k0 < BKK; k0 += 32) {
            bf16x8 a[4], b[4];
            for (int i = 0; i < 4; ++i)
                a[i] = *reinterpret_cast<const bf16x8*>(&sm.st.As[wr * 64 + i * 16 + r][k0 + 8 * g]);
            for (int j = 0; j < 4; ++j)
                b[j] = *reinterpret_cast<const bf16x8*>(&sm.st.Bs[wc * 64 + j * 16 + r][k0 + 8 * g]);
            for (int i = 0; i < 4; ++i)
                for (int j = 0; j < 4; ++j)
                    acc[i][j] = __builtin_amdgcn_mfma_f32_16x16x32_bf16(a[i], b[j], acc[i][j], 0, 0, 0);
        }
    }

    __syncthreads();

    const int e0  = n0 + wc * 64;
    const int sec = e0 / DMODEL;
    const int h   = (e0 % DMODEL) / HDIM;
    const int row0 = m0 + wr * 64;
    const int b   = row0 >> 12;
    const int l0  = row0 & (L_SEQ - 1);
    unsigned short (*ep)[72] = sm.ep[wid];

    if (sec < 2) {
        const float* nw = (sec == 0) ? qw : kw;
        float wv[4];
        for (int j = 0; j < 4; ++j) wv[j] = nw[j * 16 + r];
        for (int i = 0; i < 4; ++i) {
            for (int t = 0; t < 4; ++t) {
                float ss = acc[i][0][t] * acc[i][0][t] + acc[i][1][t] * acc[i][1][t]
                         + acc[i][2][t] * acc[i][2][t] + acc[i][3][t] * acc[i][3][t];
                ss += __shfl_xor(ss, 1);
                ss += __shfl_xor(ss, 2);
                ss += __shfl_xor(ss, 4);
                ss += __shfl_xor(ss, 8);
                float inv = rsqrtf(ss * (1.f / 64.f) + 1e-6f);
                int lr = i * 16 + 4 * g + t;
                int l  = l0 + lr;
                float qn[4];
                for (int j = 0; j < 4; ++j) qn[j] = acc[i][j][t] * inv * wv[j];
                for (int j = 0; j < 4; ++j) {
                    int d = j * 16 + r;
                    float c = cosb[l * HDIM + d], s = sinb[l * HDIM + d];
                    float sgn = (j < 2) ? -1.f : 1.f;
                    float res = qn[j] * c + sgn * qn[j ^ 2] * s;
                    if (sec == 0) res *= QSCALE;
                    ep[lr][d] = f2bf(res);
                }
            }
        }
        unsigned short* dst = ((sec == 0) ? Qb : Kb)
            + ((size_t)(b * NHEAD + h) * L_SEQ + l0) * HDIM;
        for (int it = 0; it < 8; ++it) {
            int idx = it * 64 + lane;
            int lr = idx >> 3, ch = (idx & 7) * 8;
            ushort8_t v = *reinterpret_cast<const ushort8_t*>(&ep[lr][ch]);
            *reinterpret_cast<ushort8_t*>(&dst[(size_t)lr * HDIM + ch]) = v;
        }
    } else {
        for (int i = 0; i < 4; ++i)
            for (int t = 0; t < 4; ++t) {
                int lr = i * 16 + 4 * g + t;
                for (int j = 0; j < 4; ++j)
                    ep[j * 16 + r][lr] = f2bf(acc[i][j][t]);
            }
        unsigned short* dst = Vt + ((size_t)(b * NHEAD + h) * HDIM) * L_SEQ + l0;
        for (int it = 0; it < 8; ++it) {
            int idx = it * 64 + lane;
            int d = idx >> 3, ch = (idx & 7) * 8;
            ushort8_t v = *reinterpret_cast<const ushort8_t*>(&ep[d][ch]);
            *reinterpret_cast<ushort8_t*>(&dst[(size_t)d * L_SEQ + ch]) = v;
        }
    }
}

// ------- bf16 GEMM: C[M][N] = A[M][K] * Bt[N][K]^T (fp32 out) -------------
// 1-D grid of 384, XCD-swizzled: wgid = (lin%8)*48 + lin/8.
__global__ __launch_bounds__(256) void gemm_bf16_nt(
    const unsigned short* __restrict__ A, const unsigned short* __restrict__ Bt,
    float* __restrict__ C, int M, int N, int K)
{
    __shared__ unsigned short As[BM][BKK];
    __shared__ unsigned short Bs[BN][BKK];
    const int lin = blockIdx.x;                      // 0..383
    const int wgid = (lin & 7) * 48 + (lin >> 3);
    const int bx = wgid % 6, by = wgid / 6;
    const int tid  = threadIdx.x;
    const int lane = tid & 63;
    const int wid  = tid >> 6;
    const int r = lane & 15, g = lane >> 4;
    const int wr = wid >> 1, wc = wid & 1;
    const int m0 = by * BM;
    const int n0 = bx * BN;

    f32x4 acc[4][4];
    for (int i = 0; i < 4; ++i)
        for (int j = 0; j < 4; ++j)
            acc[i][j] = (f32x4){0.f, 0.f, 0.f, 0.f};

    for (int kt = 0; kt < K; kt += BKK) {
        __syncthreads();
        for (int p = 0; p < 4; ++p) {
            int idx = wid * 64 + p * 256 + lane;
            int row = idx >> 3;
            int ch  = (idx & 7) * 8;
            gload16(&A[(size_t)(m0 + row) * K + kt + ch],
                    (char*)As + (size_t)(wid * 64 + p * 256) * 16);
            gload16(&Bt[(size_t)(n0 + row) * K + kt + ch],
                    (char*)Bs + (size_t)(wid * 64 + p * 256) * 16);
        }
        __syncthreads();
        for (int k0 = 0; k0 < BKK; k0 += 32) {
            bf16x8 a[4], b[4];
            for (int i = 0; i < 4; ++i)
                a[i] = *reinterpret_cast<const bf16x8*>(&As[wr * 64 + i * 16 + r][k0 + 8 * g]);
            for (int j = 0; j < 4; ++j)
                b[j] = *reinterpret_cast<const bf16x8*>(&Bs[wc * 64 + j * 16 + r][k0 + 8 * g]);
            for (int i = 0; i < 4; ++i)
                for (int j = 0; j < 4; ++j)
                    acc[i][j] = __builtin_amdgcn_mfma_f32_16x16x32_bf16(a[i], b[j], acc[i][j], 0, 0, 0);
        }
    }
    for (int i = 0; i < 4; ++i)
        for (int j = 0; j < 4; ++j)
            for (int t = 0; t < 4; ++t) {
                int row = m0 + wr * 64 + i * 16 + 4 * g + t;
                int col = n0 + wc * 64 + j * 16 + r;
                C[(size_t)row * N + col] = acc[i][j][t];
            }
}

// ---------------- flash attention: 32x32 MFMA, in-reg P -------------------
// R16 (measured best, passing): T15 double s-state + source-fused
// qk(t)||softmax(t-1) interleave + cvt_pk pack + VALU rowsum + separate PV.
__global__ __launch_bounds__(256, 3) void flashattn(
    const unsigned short* __restrict__ Qb, const unsigned short* __restrict__ Kb,
    const unsigned short* __restrict__ Vt, unsigned short* __restrict__ aob)
{
    __shared__ unsigned short Ksm[2][64 * 64];   // K tiles [k=64][d=64], swizzled
    __shared__ unsigned short Vsm[2][64 * 64];   // V^T tiles [d=64][k=64], swizzled

    const int lin = blockIdx.x;                 // 0..767
    const int bh = (lin & 7) + 8 * (lin >> 8);  // head -> one XCD
    const int qblk = (lin >> 3) & 31;
    const int b = bh / NHEAD, h = bh % NHEAD;
    const int tid = threadIdx.x;
    const int wid = tid >> 6, lane = tid & 63;
    const int l31 = lane & 31, half = lane >> 5;
    const int q0 = qblk * 128 + wid * 32;

    // Q as B-operand: lane holds Q[q0+l31][16*dt + 8*half + c]
    bf16x8 qf[4];
    {
        const unsigned short* Qp = Qb + ((size_t)bh * L_SEQ + q0 + l31) * HDIM + 8 * half;
        for (int dt = 0; dt < 4; ++dt)
            qf[dt] = *reinterpret_cast<const bf16x8*>(Qp + dt * 16);
    }

    const unsigned short* Kbase = Kb + (size_t)bh * L_SEQ * HDIM;
    const unsigned short* Vbase = Vt + (size_t)bh * HDIM * L_SEQ;

    const int row0 = tid >> 3;
    const int c0 = ((tid & 7) * 16) ^ ((row0 & 7) << 4);
    const char* kp0 = (const char*)(Kbase + (size_t)row0 * HDIM) + c0;
    const char* vp0 = (const char*)(Vbase + (size_t)row0 * L_SEQ) + c0;

    f32x16 o0, o1, sA0, sA1, sB0, sB1;
    for (int e = 0; e < 16; ++e) {
        o0[e] = 0.f; o1[e] = 0.f;
        sA0[e] = 0.f; sA1[e] = 0.f; sB0[e] = 0.f; sB1[e] = 0.f;
    }
    float lacc = 0.f;   // running softmax denominator for q = l31

    auto stageK = [&](int buf, int t) {
        size_t off = (size_t)t * (64 * HDIM * 2);
        gload16(kp0 + off, (char*)Ksm[buf] + wid * 1024);
        gload16(kp0 + off + 32 * HDIM * 2, (char*)Ksm[buf] + wid * 1024 + 4096);
    };
    auto stageV = [&](int buf, int t) {
        size_t off = (size_t)t * 128;
        gload16(vp0 + off, (char*)Vsm[buf] + wid * 1024);
        gload16(vp0 + off + (size_t)32 * L_SEQ * 2, (char*)Vsm[buf] + wid * 1024 + 4096);
    };

    // plain QK (prologue: no previous tile to softmax)
    auto qk = [&](f32x16& w0, f32x16& w1, const unsigned short* Kbuf) {
        const char* rp0 = (const char*)Kbuf + l31 * 128;
        const char* rp1 = rp0 + 32 * 128;
        const int sw = (l31 & 7) << 4;
        for (int dt = 0; dt < 4; ++dt) {
            int co = (dt * 32 + half * 16) ^ sw;
            bf16x8 kf0 = *reinterpret_cast<const bf16x8*>(rp0 + co);
            bf16x8 kf1 = *reinterpret_cast<const bf16x8*>(rp1 + co);
            w0 = __builtin_amdgcn_mfma_f32_32x32x16_bf16(kf0, qf[dt], w0, 0, 0, 0);
            w1 = __builtin_amdgcn_mfma_f32_32x32x16_bf16(kf1, qf[dt], w1, 0, 0, 0);
        }
    };

    // fused: QK of tile t (into w0/w1) INTERLEAVED with softmax of tile t-1
    auto qk_sm = [&](f32x16& w0, f32x16& w1, f32x16& s0, f32x16& s1,
                     const unsigned short* Kbuf, bf16x8* pa) {
        const char* rp0 = (const char*)Kbuf + l31 * 128;
        const char* rp1 = rp0 + 32 * 128;
        const int sw = (l31 & 7) << 4;
        float ts = 0.f;
#pragma unroll
        for (int dt = 0; dt < 4; ++dt) {
            int co = (dt * 32 + half * 16) ^ sw;
            bf16x8 kf0 = *reinterpret_cast<const bf16x8*>(rp0 + co);
            bf16x8 kf1 = *reinterpret_cast<const bf16x8*>(rp1 + co);
            w0 = __builtin_amdgcn_mfma_f32_32x32x16_bf16(kf0, qf[dt], w0, 0, 0, 0);
            w1 = __builtin_amdgcn_mfma_f32_32x32x16_bf16(kf1, qf[dt], w1, 0, 0, 0);
            f32x16& s = (dt & 2) ? s1 : s0;
            const int kb8 = (dt & 1) * 8;
            float p8[8];
            for (int e = 0; e < 8; ++e) p8[e] = __builtin_amdgcn_exp2f(s[kb8 + e]);
            ts += ((p8[0] + p8[1]) + (p8[2] + p8[3])) + ((p8[4] + p8[5]) + (p8[6] + p8[7]));
            unsigned A = pack2bf(p8[0], p8[1]);
            unsigned Bp = pack2bf(p8[2], p8[3]);
            unsigned C = pack2bf(p8[4], p8[5]);
            unsigned D = pack2bf(p8[6], p8[7]);
            asm("v_permlane32_swap_b32 %0, %1" : "+v"(A), "+v"(C));
            asm("v_permlane32_swap_b32 %0, %1" : "+v"(Bp), "+v"(D));
            union { unsigned u[4]; bf16x8 v; } tt;
            tt.u[0] = A; tt.u[1] = Bp; tt.u[2] = C; tt.u[3] = D;
            pa[dt] = tt.v;
            for (int e = 0; e < 8; ++e) s[kb8 + e] = 0.f;
        }
        lacc += ts;
    };

    // softmax only (final tile)
    auto softmax_pa = [&](f32x16& s0, f32x16& s1, bf16x8* pa) {
        float ts = 0.f;
        for (int kh = 0; kh < 2; ++kh) {
            f32x16& s = kh ? s1 : s0;
            for (int kk = 0; kk < 2; ++kk) {
                float p8[8];
                for (int e = 0; e < 8; ++e) p8[e] = __builtin_amdgcn_exp2f(s[8 * kk + e]);
                ts += ((p8[0] + p8[1]) + (p8[2] + p8[3])) + ((p8[4] + p8[5]) + (p8[6] + p8[7]));
                unsigned A = pack2bf(p8[0], p8[1]);
                unsigned Bp = pack2bf(p8[2], p8[3]);
                unsigned C = pack2bf(p8[4], p8[5]);
                unsigned D = pack2bf(p8[6], p8[7]);
                asm("v_permlane32_swap_b32 %0, %1" : "+v"(A), "+v"(C));
                asm("v_permlane32_swap_b32 %0, %1" : "+v"(Bp), "+v"(D));
                union { unsigned u[4]; bf16x8 v; } tt;
                tt.u[0] = A; tt.u[1] = Bp; tt.u[2] = C; tt.u[3] = D;
                pa[2 * kh + kk] = tt.v;
            }
        }
        lacc += ts;
    };

    auto pv = [&](const bf16x8* pa, const unsigned short* Vbuf) {
        const char* rp0 = (const char*)Vbuf + l31 * 128;
        const char* rp1 = rp0 + 32 * 128;
        const int sw = (l31 & 7) << 4;
        for (int kt = 0; kt < 4; ++kt) {
            int co = (kt * 32 + half * 16) ^ sw;
            bf16x8 vf0 = *reinterpret_cast<const bf16x8*>(rp0 + co);
            bf16x8 vf1 = *reinterpret_cast<const bf16x8*>(rp1 + co);
            o0 = __builtin_amdgcn_mfma_f32_32x32x16_bf16(pa[kt], vf0, o0, 0, 0, 0);
            o1 = __builtin_amdgcn_mfma_f32_32x32x16_bf16(pa[kt], vf1, o1, 0, 0, 0);
        }
    };

    // prologue: tile 0
    stageK(0, 0);
    __syncthreads();
    stageK(1, 1); stageV(0, 0);
    __builtin_amdgcn_s_setprio(1);
    qk(sA0, sA1, Ksm[0]);
    __builtin_amdgcn_s_setprio(0);
    __syncthreads();

    bf16x8 pa[4];
    // main loop: pairs (t=2i+1 odd, t=2i+2 even), t in 1..62
    for (int i = 0; i < 31; ++i) {
        int t1 = 2 * i + 1;
        stageK(0, t1 + 1); stageV(1, t1);
        __builtin_amdgcn_s_setprio(1);
        qk_sm(sB0, sB1, sA0, sA1, Ksm[1], pa);
        pv(pa, Vsm[0]);
        __builtin_amdgcn_s_setprio(0);
        __syncthreads();
        int t2 = t1 + 1;
        stageK(1, t2 + 1); stageV(0, t2);
        __builtin_amdgcn_s_setprio(1);
        qk_sm(sA0, sA1, sB0, sB1, Ksm[0], pa);
        pv(pa, Vsm[1]);
        __builtin_amdgcn_s_setprio(0);
        __syncthreads();
    }
    // peel t = 63 (odd): no stageK
    stageV(1, 63);
    __builtin_amdgcn_s_setprio(1);
    qk_sm(sB0, sB1, sA0, sA1, Ksm[1], pa);
    pv(pa, Vsm[0]);
    __builtin_amdgcn_s_setprio(0);
    __syncthreads();
    // epilogue: softmax + PV of tile 63
    softmax_pa(sB0, sB1, pa);
    pv(pa, Vsm[1]);

    // merge the two half-wave k-partitions: full l for q = l31
    float ltot = lacc + __shfl_xor(lacc, 32);

    // epilogue: O[q = (j&3)+8*(j>>2)+4*half][d = dh*32 + l31]; l[q] at lane q
    for (int j = 0; j < 16; ++j) {
        int q = (j & 3) + 8 * (j >> 2) + 4 * half;
        float linv = 1.f / __shfl(ltot, q);
        size_t base = ((size_t)(b * L_SEQ + q0 + q)) * DMODEL + h * HDIM + l31;
        aob[base] = f2bf(o0[j] * linv);
        aob[base + 32] = f2bf(o1[j] * linv);
    }
}

// ---------------- launch ----------------
extern "C" void kernel_launch(void* const* d_in, const int* in_sizes, int n_in,
                              void* d_out, int out_size, void* d_ws, size_t ws_size,
                              hipStream_t stream) {
    const float* x        = (const float*)d_in[0];
    const float* rope_cos = (const float*)d_in[1];
    const float* rope_sin = (const float*)d_in[2];
    const float* Wqkv     = (const float*)d_in[3];
    const float* Wout     = (const float*)d_in[4];
    const float* q_norm_w = (const float*)d_in[5];
    const float* k_norm_w = (const float*)d_in[6];
    float* out = (float*)d_out;

    const int BL = 2 * L_SEQ;
    const int nx    = BL * DMODEL;
    const int nwqkv = 3 * DMODEL * DMODEL;
    const int nwout = DMODEL * DMODEL;

    char* w = (char*)d_ws;
    unsigned short* xb    = (unsigned short*)w; w += (size_t)nx * 2;
    unsigned short* wqkvb = (unsigned short*)w; w += (size_t)nwqkv * 2;
    unsigned short* woutb = (unsigned short*)w; w += (size_t)nwout * 2;
    unsigned short* Qb    = (unsigned short*)w; w += (size_t)nx * 2;
    unsigned short* Kb    = (unsigned short*)w; w += (size_t)nx * 2;
    unsigned short* Vtb   = (unsigned short*)w; w += (size_t)nx * 2;
    unsigned short* aob   = (unsigned short*)w; w += (size_t)nx * 2;

    {
        int total = (nx + nwqkv + nwout) / 4;
        cvt3_f32_bf16<<<(total + 255) / 256, 256, 0, stream>>>(
            x, xb, nx, Wqkv, wqkvb, nwqkv, Wout, woutb, nwout);
    }

    // GEMM1: 1152 blocks (18 x 64), XCD-swizzled 1-D
    gemm_qkv_fused<<<1152, 256, 0, stream>>>(xb, wqkvb, rope_cos, rope_sin,
                                             q_norm_w, k_norm_w, Qb, Kb, Vtb);

    flashattn<<<768, 256, 0, stream>>>(Qb, Kb, Vtb, aob);

    // GEMM2: 384 blocks (6 x 64), XCD-swizzled 1-D
    gemm_bf16_nt<<<384, 256, 0, stream>>>(aob, woutb, out, BL, DMODEL, DMODEL);
}

// Round 19
// 206.335 us; speedup vs baseline: 1.0019x; 1.0019x over previous
//
#include <hip/hip_runtime.h>
#include <hip/hip_bf16.h>

typedef float f32x4 __attribute__((ext_vector_type(4)));
typedef float f32x16 __attribute__((ext_vector_type(16)));
typedef short bf16x8 __attribute__((ext_vector_type(8)));
typedef unsigned short ushort8_t __attribute__((ext_vector_type(8)));

#define L_SEQ 4096
#define DMODEL 768
#define NHEAD 12
#define HDIM 64
#define QSCALE (0.125f * 1.44269504f)   // 1/sqrt(64) * log2(e)

__device__ __forceinline__ unsigned short f2bf(float f) {
    __hip_bfloat16 h = __float2bfloat16(f);
    return *reinterpret_cast<unsigned short*>(&h);
}

// HW packed conversion: dst.lo = bf16(a), dst.hi = bf16(b)  (T12 recipe)
__device__ __forceinline__ unsigned pack2bf(float a, float b) {
    unsigned r;
    asm("v_cvt_pk_bf16_f32 %0, %1, %2" : "=v"(r) : "v"(a), "v"(b));
    return r;
}

__device__ __forceinline__ void gload16(const void* g, void* l) {
    __builtin_amdgcn_global_load_lds(
        (const __attribute__((address_space(1))) unsigned int*)g,
        (__attribute__((address_space(3))) unsigned int*)l, 16, 0, 0);
}

// ---------------- fp32 -> bf16 conversion (3 tensors, one dispatch) -------
__global__ __launch_bounds__(256) void cvt3_f32_bf16(
    const float* __restrict__ a, unsigned short* __restrict__ oa, int na,
    const float* __restrict__ bsrc, unsigned short* __restrict__ ob, int nb,
    const float* __restrict__ csrc, unsigned short* __restrict__ oc, int nc)
{
    int i = (blockIdx.x * 256 + threadIdx.x) * 4;
    const float* in; unsigned short* out;
    if (i < na) { in = a; out = oa; }
    else if (i < na + nb) { in = bsrc; out = ob; i -= na; }
    else if (i < na + nb + nc) { in = csrc; out = oc; i -= na + nb; }
    else return;
    float4 v = *reinterpret_cast<const float4*>(in + i);
    ushort4 o;
    o.x = f2bf(v.x); o.y = f2bf(v.y); o.z = f2bf(v.z); o.w = f2bf(v.w);
    *reinterpret_cast<ushort4*>(out + i) = o;
}

#define BM 128
#define BN 128
#define BKK 64

// ------- GEMM1 + fused RMSnorm/RoPE/scale/transpose epilogue --------------
// 1-D grid of 1152, XCD-swizzled: wgid = (lin%8)*144 + lin/8.
__global__ __launch_bounds__(256) void gemm_qkv_fused(
    const unsigned short* __restrict__ A, const unsigned short* __restrict__ Bt,
    const float* __restrict__ cosb, const float* __restrict__ sinb,
    const float* __restrict__ qw, const float* __restrict__ kw,
    unsigned short* __restrict__ Qb, unsigned short* __restrict__ Kb,
    unsigned short* __restrict__ Vt)
{
    __shared__ union SM {
        struct { unsigned short As[BM][BKK]; unsigned short Bs[BN][BKK]; } st;
        unsigned short ep[4][64][72];
    } sm;

    const int K = DMODEL;
    const int lin = blockIdx.x;                       // 0..1151
    const int wgid = (lin & 7) * 144 + (lin >> 3);    // XCD-contiguous
    const int bx = wgid % 18, by = wgid / 18;
    const int tid  = threadIdx.x;
    const int lane = tid & 63;
    const int wid  = tid >> 6;
    const int r = lane & 15, g = lane >> 4;
    const int wr = wid >> 1, wc = wid & 1;
    const int m0 = by * BM;
    const int n0 = bx * BN;

    f32x4 acc[4][4];
    for (int i = 0; i < 4; ++i)
        for (int j = 0; j < 4; ++j)
            acc[i][j] = (f32x4){0.f, 0.f, 0.f, 0.f};

    for (int kt = 0; kt < K; kt += BKK) {
        __syncthreads();
        for (int p = 0; p < 4; ++p) {
            int idx = wid * 64 + p * 256 + lane;
            int row = idx >> 3;
            int ch  = (idx & 7) * 8;
            gload16(&A[(size_t)(m0 + row) * K + kt + ch],
                    (char*)sm.st.As + (size_t)(wid * 64 + p * 256) * 16);
            gload16(&Bt[(size_t)(n0 + row) * K + kt + ch],
                    (char*)sm.st.Bs + (size_t)(wid * 64 + p * 256) * 16);
        }
        __syncthreads();
        for (int k0 = 0; k0 < BKK; k0 += 32) {
            bf16x8 a[4], b[4];
            for (int i = 0; i < 4; ++i)
                a[i] = *reinterpret_cast<const bf16x8*>(&sm.st.As[wr * 64 + i * 16 + r][k0 + 8 * g]);
            for (int j = 0; j < 4; ++j)
                b[j] = *reinterpret_cast<const bf16x8*>(&sm.st.Bs[wc * 64 + j * 16 + r][k0 + 8 * g]);
            for (int i = 0; i < 4; ++i)
                for (int j = 0; j < 4; ++j)
                    acc[i][j] = __builtin_amdgcn_mfma_f32_16x16x32_bf16(a[i], b[j], acc[i][j], 0, 0, 0);
        }
    }

    __syncthreads();

    const int e0  = n0 + wc * 64;
    const int sec = e0 / DMODEL;
    const int h   = (e0 % DMODEL) / HDIM;
    const int row0 = m0 + wr * 64;
    const int b   = row0 >> 12;
    const int l0  = row0 & (L_SEQ - 1);
    unsigned short (*ep)[72] = sm.ep[wid];

    if (sec < 2) {
        const float* nw = (sec == 0) ? qw : kw;
        float wv[4];
        for (int j = 0; j < 4; ++j) wv[j] = nw[j * 16 + r];
        for (int i = 0; i < 4; ++i) {
            for (int t = 0; t < 4; ++t) {
                float ss = acc[i][0][t] * acc[i][0][t] + acc[i][1][t] * acc[i][1][t]
                         + acc[i][2][t] * acc[i][2][t] + acc[i][3][t] * acc[i][3][t];
                ss += __shfl_xor(ss, 1);
                ss += __shfl_xor(ss, 2);
                ss += __shfl_xor(ss, 4);
                ss += __shfl_xor(ss, 8);
                float inv = rsqrtf(ss * (1.f / 64.f) + 1e-6f);
                int lr = i * 16 + 4 * g + t;
                int l  = l0 + lr;
                float qn[4];
                for (int j = 0; j < 4; ++j) qn[j] = acc[i][j][t] * inv * wv[j];
                for (int j = 0; j < 4; ++j) {
                    int d = j * 16 + r;
                    float c = cosb[l * HDIM + d], s = sinb[l * HDIM + d];
                    float sgn = (j < 2) ? -1.f : 1.f;
                    float res = qn[j] * c + sgn * qn[j ^ 2] * s;
                    if (sec == 0) res *= QSCALE;
                    ep[lr][d] = f2bf(res);
                }
            }
        }
        unsigned short* dst = ((sec == 0) ? Qb : Kb)
            + ((size_t)(b * NHEAD + h) * L_SEQ + l0) * HDIM;
        for (int it = 0; it < 8; ++it) {
            int idx = it * 64 + lane;
            int lr = idx >> 3, ch = (idx & 7) * 8;
            ushort8_t v = *reinterpret_cast<const ushort8_t*>(&ep[lr][ch]);
            *reinterpret_cast<ushort8_t*>(&dst[(size_t)lr * HDIM + ch]) = v;
        }
    } else {
        for (int i = 0; i < 4; ++i)
            for (int t = 0; t < 4; ++t) {
                int lr = i * 16 + 4 * g + t;
                for (int j = 0; j < 4; ++j)
                    ep[j * 16 + r][lr] = f2bf(acc[i][j][t]);
            }
        unsigned short* dst = Vt + ((size_t)(b * NHEAD + h) * HDIM) * L_SEQ + l0;
        for (int it = 0; it < 8; ++it) {
            int idx = it * 64 + lane;
            int d = idx >> 3, ch = (idx & 7) * 8;
            ushort8_t v = *reinterpret_cast<const ushort8_t*>(&ep[d][ch]);
            *reinterpret_cast<ushort8_t*>(&dst[(size_t)d * L_SEQ + ch]) = v;
        }
    }
}

// ------- bf16 GEMM: C[M][N] = A[M][K] * Bt[N][K]^T (fp32 out) -------------
// 1-D grid of 384, XCD-swizzled: wgid = (lin%8)*48 + lin/8.
__global__ __launch_bounds__(256) void gemm_bf16_nt(
    const unsigned short* __restrict__ A, const unsigned short* __restrict__ Bt,
    float* __restrict__ C, int M, int N, int K)
{
    __shared__ unsigned short As[BM][BKK];
    __shared__ unsigned short Bs[BN][BKK];
    const int lin = blockIdx.x;                      // 0..383
    const int wgid = (lin & 7) * 48 + (lin >> 3);
    const int bx = wgid % 6, by = wgid / 6;
    const int tid  = threadIdx.x;
    const int lane = tid & 63;
    const int wid  = tid >> 6;
    const int r = lane & 15, g = lane >> 4;
    const int wr = wid >> 1, wc = wid & 1;
    const int m0 = by * BM;
    const int n0 = bx * BN;

    f32x4 acc[4][4];
    for (int i = 0; i < 4; ++i)
        for (int j = 0; j < 4; ++j)
            acc[i][j] = (f32x4){0.f, 0.f, 0.f, 0.f};

    for (int kt = 0; kt < K; kt += BKK) {
        __syncthreads();
        for (int p = 0; p < 4; ++p) {
            int idx = wid * 64 + p * 256 + lane;
            int row = idx >> 3;
            int ch  = (idx & 7) * 8;
            gload16(&A[(size_t)(m0 + row) * K + kt + ch],
                    (char*)As + (size_t)(wid * 64 + p * 256) * 16);
            gload16(&Bt[(size_t)(n0 + row) * K + kt + ch],
                    (char*)Bs + (size_t)(wid * 64 + p * 256) * 16);
        }
        __syncthreads();
        for (int k0 = 0; k0 < BKK; k0 += 32) {
            bf16x8 a[4], b[4];
            for (int i = 0; i < 4; ++i)
                a[i] = *reinterpret_cast<const bf16x8*>(&As[wr * 64 + i * 16 + r][k0 + 8 * g]);
            for (int j = 0; j < 4; ++j)
                b[j] = *reinterpret_cast<const bf16x8*>(&Bs[wc * 64 + j * 16 + r][k0 + 8 * g]);
            for (int i = 0; i < 4; ++i)
                for (int j = 0; j < 4; ++j)
                    acc[i][j] = __builtin_amdgcn_mfma_f32_16x16x32_bf16(a[i], b[j], acc[i][j], 0, 0, 0);
        }
    }
    for (int i = 0; i < 4; ++i)
        for (int j = 0; j < 4; ++j)
            for (int t = 0; t < 4; ++t) {
                int row = m0 + wr * 64 + i * 16 + 4 * g + t;
                int col = n0 + wc * 64 + j * 16 + r;
                C[(size_t)row * N + col] = acc[i][j][t];
            }
}

// ---------------- flash attention: 32x32 MFMA, in-reg P -------------------
// R16 structure + one-time phase stagger: odd blocks sleep ~400cyc after the
// prologue so the two co-resident waves on each SIMD run phase-offset ->
// block A's MFMA phases overlap block B's VALU/trans phases (m114).
__global__ __launch_bounds__(256, 3) void flashattn(
    const unsigned short* __restrict__ Qb, const unsigned short* __restrict__ Kb,
    const unsigned short* __restrict__ Vt, unsigned short* __restrict__ aob)
{
    __shared__ unsigned short Ksm[2][64 * 64];   // K tiles [k=64][d=64], swizzled
    __shared__ unsigned short Vsm[2][64 * 64];   // V^T tiles [d=64][k=64], swizzled

    const int lin = blockIdx.x;                 // 0..767
    const int bh = (lin & 7) + 8 * (lin >> 8);  // head -> one XCD
    const int qblk = (lin >> 3) & 31;
    const int b = bh / NHEAD, h = bh % NHEAD;
    const int tid = threadIdx.x;
    const int wid = tid >> 6, lane = tid & 63;
    const int l31 = lane & 31, half = lane >> 5;
    const int q0 = qblk * 128 + wid * 32;

    // Q as B-operand: lane holds Q[q0+l31][16*dt + 8*half + c]
    bf16x8 qf[4];
    {
        const unsigned short* Qp = Qb + ((size_t)bh * L_SEQ + q0 + l31) * HDIM + 8 * half;
        for (int dt = 0; dt < 4; ++dt)
            qf[dt] = *reinterpret_cast<const bf16x8*>(Qp + dt * 16);
    }

    const unsigned short* Kbase = Kb + (size_t)bh * L_SEQ * HDIM;
    const unsigned short* Vbase = Vt + (size_t)bh * HDIM * L_SEQ;

    const int row0 = tid >> 3;
    const int c0 = ((tid & 7) * 16) ^ ((row0 & 7) << 4);
    const char* kp0 = (const char*)(Kbase + (size_t)row0 * HDIM) + c0;
    const char* vp0 = (const char*)(Vbase + (size_t)row0 * L_SEQ) + c0;

    f32x16 o0, o1, sA0, sA1, sB0, sB1;
    for (int e = 0; e < 16; ++e) {
        o0[e] = 0.f; o1[e] = 0.f;
        sA0[e] = 0.f; sA1[e] = 0.f; sB0[e] = 0.f; sB1[e] = 0.f;
    }
    float lacc = 0.f;   // running softmax denominator for q = l31

    auto stageK = [&](int buf, int t) {
        size_t off = (size_t)t * (64 * HDIM * 2);
        gload16(kp0 + off, (char*)Ksm[buf] + wid * 1024);
        gload16(kp0 + off + 32 * HDIM * 2, (char*)Ksm[buf] + wid * 1024 + 4096);
    };
    auto stageV = [&](int buf, int t) {
        size_t off = (size_t)t * 128;
        gload16(vp0 + off, (char*)Vsm[buf] + wid * 1024);
        gload16(vp0 + off + (size_t)32 * L_SEQ * 2, (char*)Vsm[buf] + wid * 1024 + 4096);
    };

    // plain QK (prologue: no previous tile to softmax)
    auto qk = [&](f32x16& w0, f32x16& w1, const unsigned short* Kbuf) {
        const char* rp0 = (const char*)Kbuf + l31 * 128;
        const char* rp1 = rp0 + 32 * 128;
        const int sw = (l31 & 7) << 4;
        for (int dt = 0; dt < 4; ++dt) {
            int co = (dt * 32 + half * 16) ^ sw;
            bf16x8 kf0 = *reinterpret_cast<const bf16x8*>(rp0 + co);
            bf16x8 kf1 = *reinterpret_cast<const bf16x8*>(rp1 + co);
            w0 = __builtin_amdgcn_mfma_f32_32x32x16_bf16(kf0, qf[dt], w0, 0, 0, 0);
            w1 = __builtin_amdgcn_mfma_f32_32x32x16_bf16(kf1, qf[dt], w1, 0, 0, 0);
        }
    };

    // fused: QK of tile t (into w0/w1) INTERLEAVED with softmax of tile t-1
    auto qk_sm = [&](f32x16& w0, f32x16& w1, f32x16& s0, f32x16& s1,
                     const unsigned short* Kbuf, bf16x8* pa) {
        const char* rp0 = (const char*)Kbuf + l31 * 128;
        const char* rp1 = rp0 + 32 * 128;
        const int sw = (l31 & 7) << 4;
        float ts = 0.f;
#pragma unroll
        for (int dt = 0; dt < 4; ++dt) {
            int co = (dt * 32 + half * 16) ^ sw;
            bf16x8 kf0 = *reinterpret_cast<const bf16x8*>(rp0 + co);
            bf16x8 kf1 = *reinterpret_cast<const bf16x8*>(rp1 + co);
            w0 = __builtin_amdgcn_mfma_f32_32x32x16_bf16(kf0, qf[dt], w0, 0, 0, 0);
            w1 = __builtin_amdgcn_mfma_f32_32x32x16_bf16(kf1, qf[dt], w1, 0, 0, 0);
            f32x16& s = (dt & 2) ? s1 : s0;
            const int kb8 = (dt & 1) * 8;
            float p8[8];
            for (int e = 0; e < 8; ++e) p8[e] = __builtin_amdgcn_exp2f(s[kb8 + e]);
            ts += ((p8[0] + p8[1]) + (p8[2] + p8[3])) + ((p8[4] + p8[5]) + (p8[6] + p8[7]));
            unsigned A = pack2bf(p8[0], p8[1]);
            unsigned Bp = pack2bf(p8[2], p8[3]);
            unsigned C = pack2bf(p8[4], p8[5]);
            unsigned D = pack2bf(p8[6], p8[7]);
            asm("v_permlane32_swap_b32 %0, %1" : "+v"(A), "+v"(C));
            asm("v_permlane32_swap_b32 %0, %1" : "+v"(Bp), "+v"(D));
            union { unsigned u[4]; bf16x8 v; } tt;
            tt.u[0] = A; tt.u[1] = Bp; tt.u[2] = C; tt.u[3] = D;
            pa[dt] = tt.v;
            for (int e = 0; e < 8; ++e) s[kb8 + e] = 0.f;
        }
        lacc += ts;
    };

    // softmax only (final tile)
    auto softmax_pa = [&](f32x16& s0, f32x16& s1, bf16x8* pa) {
        float ts = 0.f;
        for (int kh = 0; kh < 2; ++kh) {
            f32x16& s = kh ? s1 : s0;
            for (int kk = 0; kk < 2; ++kk) {
                float p8[8];
                for (int e = 0; e < 8; ++e) p8[e] = __builtin_amdgcn_exp2f(s[8 * kk + e]);
                ts += ((p8[0] + p8[1]) + (p8[2] + p8[3])) + ((p8[4] + p8[5]) + (p8[6] + p8[7]));
                unsigned A = pack2bf(p8[0], p8[1]);
                unsigned Bp = pack2bf(p8[2], p8[3]);
                unsigned C = pack2bf(p8[4], p8[5]);
                unsigned D = pack2bf(p8[6], p8[7]);
                asm("v_permlane32_swap_b32 %0, %1" : "+v"(A), "+v"(C));
                asm("v_permlane32_swap_b32 %0, %1" : "+v"(Bp), "+v"(D));
                union { unsigned u[4]; bf16x8 v; } tt;
                tt.u[0] = A; tt.u[1] = Bp; tt.u[2] = C; tt.u[3] = D;
                pa[2 * kh + kk] = tt.v;
            }
        }
        lacc += ts;
    };

    auto pv = [&](const bf16x8* pa, const unsigned short* Vbuf) {
        const char* rp0 = (const char*)Vbuf + l31 * 128;
        const char* rp1 = rp0 + 32 * 128;
        const int sw = (l31 & 7) << 4;
        for (int kt = 0; kt < 4; ++kt) {
            int co = (kt * 32 + half * 16) ^ sw;
            bf16x8 vf0 = *reinterpret_cast<const bf16x8*>(rp0 + co);
            bf16x8 vf1 = *reinterpret_cast<const bf16x8*>(rp1 + co);
            o0 = __builtin_amdgcn_mfma_f32_32x32x16_bf16(pa[kt], vf0, o0, 0, 0, 0);
            o1 = __builtin_amdgcn_mfma_f32_32x32x16_bf16(pa[kt], vf1, o1, 0, 0, 0);
        }
    };

    // prologue: tile 0
    stageK(0, 0);
    __syncthreads();
    // one-time phase stagger for odd blocks (~384 cyc): de-phases the two
    // co-resident blocks on each CU so MFMA and VALU phases interleave.
    if (lin & 1) asm volatile("s_sleep 6");
    stageK(1, 1); stageV(0, 0);
    __builtin_amdgcn_s_setprio(1);
    qk(sA0, sA1, Ksm[0]);
    __builtin_amdgcn_s_setprio(0);
    __syncthreads();

    bf16x8 pa[4];
    // main loop: pairs (t=2i+1 odd, t=2i+2 even), t in 1..62
    for (int i = 0; i < 31; ++i) {
        int t1 = 2 * i + 1;
        stageK(0, t1 + 1); stageV(1, t1);
        __builtin_amdgcn_s_setprio(1);
        qk_sm(sB0, sB1, sA0, sA1, Ksm[1], pa);
        pv(pa, Vsm[0]);
        __builtin_amdgcn_s_setprio(0);
        __syncthreads();
        int t2 = t1 + 1;
        stageK(1, t2 + 1); stageV(0, t2);
        __builtin_amdgcn_s_setprio(1);
        qk_sm(sA0, sA1, sB0, sB1, Ksm[0], pa);
        pv(pa, Vsm[1]);
        __builtin_amdgcn_s_setprio(0);
        __syncthreads();
    }
    // peel t = 63 (odd): no stageK
    stageV(1, 63);
    __builtin_amdgcn_s_setprio(1);
    qk_sm(sB0, sB1, sA0, sA1, Ksm[1], pa);
    pv(pa, Vsm[0]);
    __builtin_amdgcn_s_setprio(0);
    __syncthreads();
    // epilogue: softmax + PV of tile 63
    softmax_pa(sB0, sB1, pa);
    pv(pa, Vsm[1]);

    // merge the two half-wave k-partitions: full l for q = l31
    float ltot = lacc + __shfl_xor(lacc, 32);

    // epilogue: O[q = (j&3)+8*(j>>2)+4*half][d = dh*32 + l31]; l[q] at lane q
    for (int j = 0; j < 16; ++j) {
        int q = (j & 3) + 8 * (j >> 2) + 4 * half;
        float linv = 1.f / __shfl(ltot, q);
        size_t base = ((size_t)(b * L_SEQ + q0 + q)) * DMODEL + h * HDIM + l31;
        aob[base] = f2bf(o0[j] * linv);
        aob[base + 32] = f2bf(o1[j] * linv);
    }
}

// ---------------- launch ----------------
extern "C" void kernel_launch(void* const* d_in, const int* in_sizes, int n_in,
                              void* d_out, int out_size, void* d_ws, size_t ws_size,
                              hipStream_t stream) {
    const float* x        = (const float*)d_in[0];
    const float* rope_cos = (const float*)d_in[1];
    const float* rope_sin = (const float*)d_in[2];
    const float* Wqkv     = (const float*)d_in[3];
    const float* Wout     = (const float*)d_in[4];
    const float* q_norm_w = (const float*)d_in[5];
    const float* k_norm_w = (const float*)d_in[6];
    float* out = (float*)d_out;

    const int BL = 2 * L_SEQ;
    const int nx    = BL * DMODEL;
    const int nwqkv = 3 * DMODEL * DMODEL;
    const int nwout = DMODEL * DMODEL;

    char* w = (char*)d_ws;
    unsigned short* xb    = (unsigned short*)w; w += (size_t)nx * 2;
    unsigned short* wqkvb = (unsigned short*)w; w += (size_t)nwqkv * 2;
    unsigned short* woutb = (unsigned short*)w; w += (size_t)nwout * 2;
    unsigned short* Qb    = (unsigned short*)w; w += (size_t)nx * 2;
    unsigned short* Kb    = (unsigned short*)w; w += (size_t)nx * 2;
    unsigned short* Vtb   = (unsigned short*)w; w += (size_t)nx * 2;
    unsigned short* aob   = (unsigned short*)w; w += (size_t)nx * 2;

    {
        int total = (nx + nwqkv + nwout) / 4;
        cvt3_f32_bf16<<<(total + 255) / 256, 256, 0, stream>>>(
            x, xb, nx, Wqkv, wqkvb, nwqkv, Wout, woutb, nwout);
    }

    // GEMM1: 1152 blocks (18 x 64), XCD-swizzled 1-D
    gemm_qkv_fused<<<1152, 256, 0, stream>>>(xb, wqkvb, rope_cos, rope_sin,
                                             q_norm_w, k_norm_w, Qb, Kb, Vtb);

    flashattn<<<768, 256, 0, stream>>>(Qb, Kb, Vtb, aob);

    // GEMM2: 384 blocks (6 x 64), XCD-swizzled 1-D
    gemm_bf16_nt<<<384, 256, 0, stream>>>(aob, woutb, out, BL, DMODEL, DMODEL);
}